// Round 1
// baseline (1568.659 us; speedup 1.0000x reference)
//
#include <hip/hip_runtime.h>

#define N_NODES 1000000
#define N_EDGES 16000000

// K1: g1 = feat*norm ; zero agg1, agg2
__global__ void k1_prep(const float* __restrict__ feat, const float* __restrict__ norm,
                        float* __restrict__ g1, float* __restrict__ agg1,
                        float* __restrict__ agg2, int n) {
    int stride = gridDim.x * blockDim.x;
    for (int i = blockIdx.x * blockDim.x + threadIdx.x; i < n; i += stride) {
        g1[i] = feat[i] * norm[i];
        agg1[i] = 0.0f;
        agg2[i] = 0.0f;
    }
}

// Edge scatter: agg[dst[e]] += val[src[e]]  (vectorized index loads, 4 edges/iter)
__global__ void k_edge_scatter(const int* __restrict__ src, const int* __restrict__ dst,
                               const float* __restrict__ val, float* __restrict__ agg,
                               int nE) {
    int stride = gridDim.x * blockDim.x;
    int nE4 = nE >> 2;
    const int4* src4 = (const int4*)src;
    const int4* dst4 = (const int4*)dst;
    for (int i = blockIdx.x * blockDim.x + threadIdx.x; i < nE4; i += stride) {
        int4 s = src4[i];
        int4 d = dst4[i];
        atomicAdd(&agg[d.x], val[s.x]);
        atomicAdd(&agg[d.y], val[s.y]);
        atomicAdd(&agg[d.z], val[s.z]);
        atomicAdd(&agg[d.w], val[s.w]);
    }
    // tail (nE not multiple of 4 — not hit for 16M, kept for safety)
    int base = nE4 << 2;
    for (int e = base + blockIdx.x * blockDim.x + threadIdx.x; e < nE; e += stride) {
        atomicAdd(&agg[dst[e]], val[src[e]]);
    }
}

// K3: t[v] = norm[v] * sum_j relu(agg1[v]*norm[v]*W1[j] + b1[j]) * W2[j]
__global__ void k3_mid(const float* __restrict__ agg1, const float* __restrict__ norm,
                       const float* __restrict__ W1, const float* __restrict__ b1,
                       const float* __restrict__ W2, float* __restrict__ t, int n) {
    float w10 = W1[0], w11 = W1[1], w12 = W1[2];
    float b10 = b1[0], b11 = b1[1], b12 = b1[2];
    float w20 = W2[0], w21 = W2[1], w22 = W2[2];
    int stride = gridDim.x * blockDim.x;
    for (int i = blockIdx.x * blockDim.x + threadIdx.x; i < n; i += stride) {
        float nv = norm[i];
        float s = agg1[i] * nv;
        float h0 = fmaxf(fmaf(s, w10, b10), 0.0f);
        float h1 = fmaxf(fmaf(s, w11, b11), 0.0f);
        float h2 = fmaxf(fmaf(s, w12, b12), 0.0f);
        t[i] = nv * (h0 * w20 + h1 * w21 + h2 * w22);
    }
}

// K5: out[v] = relu(norm[v]*agg2[v] + b2)
__global__ void k5_out(const float* __restrict__ agg2, const float* __restrict__ norm,
                       const float* __restrict__ b2, float* __restrict__ out, int n) {
    float b = b2[0];
    int stride = gridDim.x * blockDim.x;
    for (int i = blockIdx.x * blockDim.x + threadIdx.x; i < n; i += stride) {
        out[i] = fmaxf(fmaf(agg2[i] * norm[i], 1.0f, b), 0.0f);
    }
}

extern "C" void kernel_launch(void* const* d_in, const int* in_sizes, int n_in,
                              void* d_out, int out_size, void* d_ws, size_t ws_size,
                              hipStream_t stream) {
    const float* feat = (const float*)d_in[0];
    const float* norm = (const float*)d_in[1];
    const int*   src  = (const int*)d_in[2];
    const int*   dst  = (const int*)d_in[3];
    const float* W1   = (const float*)d_in[4];
    const float* b1   = (const float*)d_in[5];
    const float* W2   = (const float*)d_in[6];
    const float* b2   = (const float*)d_in[7];
    float* out = (float*)d_out;

    int nN = in_sizes[0];   // 1,000,000
    int nE = in_sizes[2];   // 16,000,000

    float* g1   = (float*)d_ws;            // reused as t after edge pass 1
    float* agg1 = g1 + nN;
    float* agg2 = agg1 + nN;

    const int BLK = 256;
    int nodeBlocks = (nN + BLK - 1) / BLK;
    if (nodeBlocks > 2048) nodeBlocks = 2048;
    int edgeBlocks = 2048;

    k1_prep<<<nodeBlocks, BLK, 0, stream>>>(feat, norm, g1, agg1, agg2, nN);
    k_edge_scatter<<<edgeBlocks, BLK, 0, stream>>>(src, dst, g1, agg1, nE);
    k3_mid<<<nodeBlocks, BLK, 0, stream>>>(agg1, norm, W1, b1, W2, g1, nN);
    k_edge_scatter<<<edgeBlocks, BLK, 0, stream>>>(src, dst, g1, agg2, nE);
    k5_out<<<nodeBlocks, BLK, 0, stream>>>(agg2, norm, b2, out, nN);
}

// Round 2
// 804.509 us; speedup vs baseline: 1.9498x; 1.9498x over previous
//
#include <hip/hip_runtime.h>

#define BSHIFT 11
#define BSZ (1 << BSHIFT)          // 2048 nodes per bucket
#define NBIN_BLOCKS 1024

// ---------------- node-map kernels ----------------

// g1 = feat*norm ; zero agg1/agg2 (zeroing needed only for fallback path; cheap)
__global__ void k1_prep(const float* __restrict__ feat, const float* __restrict__ norm,
                        float* __restrict__ g1, float* __restrict__ agg1,
                        float* __restrict__ agg2, int n) {
    int stride = gridDim.x * blockDim.x;
    for (int i = blockIdx.x * blockDim.x + threadIdx.x; i < n; i += stride) {
        g1[i] = feat[i] * norm[i];
        agg1[i] = 0.0f;
        agg2[i] = 0.0f;
    }
}

// t[v] = norm[v] * sum_j relu(agg1[v]*norm[v]*W1[j] + b1[j]) * W2[j]
__global__ void k3_mid(const float* __restrict__ agg1, const float* __restrict__ norm,
                       const float* __restrict__ W1, const float* __restrict__ b1,
                       const float* __restrict__ W2, float* __restrict__ t, int n) {
    float w10 = W1[0], w11 = W1[1], w12 = W1[2];
    float b10 = b1[0], b11 = b1[1], b12 = b1[2];
    float w20 = W2[0], w21 = W2[1], w22 = W2[2];
    int stride = gridDim.x * blockDim.x;
    for (int i = blockIdx.x * blockDim.x + threadIdx.x; i < n; i += stride) {
        float nv = norm[i];
        float s = agg1[i] * nv;
        float h0 = fmaxf(fmaf(s, w10, b10), 0.0f);
        float h1 = fmaxf(fmaf(s, w11, b11), 0.0f);
        float h2 = fmaxf(fmaf(s, w12, b12), 0.0f);
        t[i] = nv * (h0 * w20 + h1 * w21 + h2 * w22);
    }
}

// out[v] = relu(norm[v]*agg2[v] + b2)
__global__ void k5_out(const float* __restrict__ agg2, const float* __restrict__ norm,
                       const float* __restrict__ b2, float* __restrict__ out, int n) {
    float b = b2[0];
    int stride = gridDim.x * blockDim.x;
    for (int i = blockIdx.x * blockDim.x + threadIdx.x; i < n; i += stride) {
        out[i] = fmaxf(agg2[i] * norm[i] + b, 0.0f);
    }
}

// ---------------- binning pipeline ----------------

// H: per-block bucket histogram of dst -> counts[blk*NB + b]   (no global atomics)
__global__ void k_hist(const int* __restrict__ dst, int nE, int NB, int chunk,
                       int* __restrict__ counts) {
    extern __shared__ int lhist[];
    for (int b = threadIdx.x; b < NB; b += blockDim.x) lhist[b] = 0;
    __syncthreads();
    int lo = blockIdx.x * chunk;
    int hi = min(lo + chunk, nE);
    for (int i = lo + (int)threadIdx.x; i < hi; i += blockDim.x)
        atomicAdd(&lhist[dst[i] >> BSHIFT], 1);
    __syncthreads();
    for (int b = threadIdx.x; b < NB; b += blockDim.x)
        counts[blockIdx.x * NB + b] = lhist[b];
}

// S: column-sum -> bucket totals; exclusive scan -> base[]; per-block chunk bases.
__global__ void k_scan(const int* __restrict__ counts, int NB, int nblk,
                       int* __restrict__ chunkbase, int* __restrict__ base) {
    extern __shared__ int tot[];  // NB ints
    for (int b = threadIdx.x; b < NB; b += blockDim.x) {
        int s = 0;
        for (int k = 0; k < nblk; ++k) s += counts[k * NB + b];
        tot[b] = s;
    }
    __syncthreads();
    if (threadIdx.x == 0) {
        int run = 0;
        for (int b = 0; b < NB; ++b) { base[b] = run; run += tot[b]; }
        base[NB] = run;
    }
    __syncthreads();
    for (int b = threadIdx.x; b < NB; b += blockDim.x) {
        int run = base[b];
        for (int k = 0; k < nblk; ++k) {
            chunkbase[k * NB + b] = run;
            run += counts[k * NB + b];
        }
    }
}

// P: place packed edges into bucket-contiguous array. pack = (src<<BSHIFT)|dst_low.
__global__ void k_place(const int* __restrict__ src, const int* __restrict__ dst,
                        int nE, int NB, int chunk,
                        const int* __restrict__ chunkbase,
                        unsigned int* __restrict__ bpack) {
    extern __shared__ int lcur[];
    for (int b = threadIdx.x; b < NB; b += blockDim.x)
        lcur[b] = chunkbase[blockIdx.x * NB + b];
    __syncthreads();
    int lo = blockIdx.x * chunk;
    int hi = min(lo + chunk, nE);
    for (int i = lo + (int)threadIdx.x; i < hi; i += blockDim.x) {
        int d = dst[i];
        int b = d >> BSHIFT;
        int idx = atomicAdd(&lcur[b], 1);
        bpack[idx] = ((unsigned int)src[i] << BSHIFT) | (unsigned int)(d & (BSZ - 1));
    }
}

// B: one block per bucket — LDS accumulate, plain-store flush. No global atomics.
__global__ void k_bucket_acc(const unsigned int* __restrict__ bpack,
                             const int* __restrict__ base,
                             const float* __restrict__ val,
                             float* __restrict__ agg, int nN) {
    __shared__ float acc[BSZ];
    for (int j = threadIdx.x; j < BSZ; j += blockDim.x) acc[j] = 0.0f;
    __syncthreads();
    int b = blockIdx.x;
    int lo = base[b], hi = base[b + 1];
    for (int i = lo + (int)threadIdx.x; i < hi; i += blockDim.x) {
        unsigned int w = bpack[i];
        float v = val[w >> BSHIFT];
        atomicAdd(&acc[w & (BSZ - 1)], v);
    }
    __syncthreads();
    int node0 = b << BSHIFT;
    for (int j = threadIdx.x; j < BSZ && node0 + j < nN; j += blockDim.x)
        agg[node0 + j] = acc[j];
}

// ---------------- fallback: direct device-scope atomic scatter ----------------
__global__ void k_edge_scatter(const int* __restrict__ src, const int* __restrict__ dst,
                               const float* __restrict__ val, float* __restrict__ agg,
                               int nE) {
    int stride = gridDim.x * blockDim.x;
    for (int e = blockIdx.x * blockDim.x + threadIdx.x; e < nE; e += stride)
        atomicAdd(&agg[dst[e]], val[src[e]]);
}

static inline size_t align256(size_t x) { return (x + 255) & ~(size_t)255; }

extern "C" void kernel_launch(void* const* d_in, const int* in_sizes, int n_in,
                              void* d_out, int out_size, void* d_ws, size_t ws_size,
                              hipStream_t stream) {
    const float* feat = (const float*)d_in[0];
    const float* norm = (const float*)d_in[1];
    const int*   src  = (const int*)d_in[2];
    const int*   dst  = (const int*)d_in[3];
    const float* W1   = (const float*)d_in[4];
    const float* b1   = (const float*)d_in[5];
    const float* W2   = (const float*)d_in[6];
    const float* b2   = (const float*)d_in[7];
    float* out = (float*)d_out;

    int nN = in_sizes[0];
    int nE = in_sizes[2];
    int NB = (nN + BSZ - 1) >> BSHIFT;

    // workspace layout
    char* p = (char*)d_ws;
    size_t off = 0;
    float* g1   = (float*)(p + off); off = align256(off + (size_t)nN * 4);
    float* agg1 = (float*)(p + off); off = align256(off + (size_t)nN * 4);
    float* agg2 = (float*)(p + off); off = align256(off + (size_t)nN * 4);
    int* base      = (int*)(p + off); off = align256(off + (size_t)(NB + 1) * 4);
    int* counts    = (int*)(p + off); off = align256(off + (size_t)NBIN_BLOCKS * NB * 4);
    int* chunkbase = (int*)(p + off); off = align256(off + (size_t)NBIN_BLOCKS * NB * 4);
    unsigned int* bpack = (unsigned int*)(p + off); off = align256(off + (size_t)nE * 4);
    size_t need = off;

    const int BLK = 256;
    int nodeBlocks = (nN + BLK - 1) / BLK;
    if (nodeBlocks > 2048) nodeBlocks = 2048;

    bool packed_ok = ((size_t)nN <= ((size_t)1 << (32 - BSHIFT)));
    if (ws_size >= need && packed_ok) {
        int chunk = (nE + NBIN_BLOCKS - 1) / NBIN_BLOCKS;
        size_t ldsNB = (size_t)NB * 4;

        k1_prep<<<nodeBlocks, BLK, 0, stream>>>(feat, norm, g1, agg1, agg2, nN);
        k_hist<<<NBIN_BLOCKS, 256, ldsNB, stream>>>(dst, nE, NB, chunk, counts);
        k_scan<<<1, 512, ldsNB, stream>>>(counts, NB, NBIN_BLOCKS, chunkbase, base);
        k_place<<<NBIN_BLOCKS, 256, ldsNB, stream>>>(src, dst, nE, NB, chunk, chunkbase, bpack);
        k_bucket_acc<<<NB, 512, 0, stream>>>(bpack, base, g1, agg1, nN);
        k3_mid<<<nodeBlocks, BLK, 0, stream>>>(agg1, norm, W1, b1, W2, g1, nN);
        k_bucket_acc<<<NB, 512, 0, stream>>>(bpack, base, g1, agg2, nN);
        k5_out<<<nodeBlocks, BLK, 0, stream>>>(agg2, norm, b2, out, nN);
    } else {
        // fallback: direct atomic scatter (round-1 path)
        int edgeBlocks = 2048;
        k1_prep<<<nodeBlocks, BLK, 0, stream>>>(feat, norm, g1, agg1, agg2, nN);
        k_edge_scatter<<<edgeBlocks, BLK, 0, stream>>>(src, dst, g1, agg1, nE);
        k3_mid<<<nodeBlocks, BLK, 0, stream>>>(agg1, norm, W1, b1, W2, g1, nN);
        k_edge_scatter<<<edgeBlocks, BLK, 0, stream>>>(src, dst, g1, agg2, nE);
        k5_out<<<nodeBlocks, BLK, 0, stream>>>(agg2, norm, b2, out, nN);
    }
}

// Round 3
// 419.545 us; speedup vs baseline: 3.7390x; 1.9176x over previous
//
#include <hip/hip_runtime.h>

#define BSHIFT 11
#define BSZ (1 << BSHIFT)          // 2048 nodes per bucket
#define NBIN_BLOCKS 1024           // histogram/placement chunks

// ---------------- node-map kernels ----------------

__global__ void k1_prep(const float* __restrict__ feat, const float* __restrict__ norm,
                        float* __restrict__ g1, float* __restrict__ agg1,
                        float* __restrict__ agg2, int n) {
    int stride = gridDim.x * blockDim.x;
    for (int i = blockIdx.x * blockDim.x + threadIdx.x; i < n; i += stride) {
        g1[i] = feat[i] * norm[i];
        agg1[i] = 0.0f;
        agg2[i] = 0.0f;
    }
}

__global__ void k3_mid(const float* __restrict__ agg1, const float* __restrict__ norm,
                       const float* __restrict__ W1, const float* __restrict__ b1,
                       const float* __restrict__ W2, float* __restrict__ t, int n) {
    float w10 = W1[0], w11 = W1[1], w12 = W1[2];
    float b10 = b1[0], b11 = b1[1], b12 = b1[2];
    float w20 = W2[0], w21 = W2[1], w22 = W2[2];
    int stride = gridDim.x * blockDim.x;
    for (int i = blockIdx.x * blockDim.x + threadIdx.x; i < n; i += stride) {
        float nv = norm[i];
        float s = agg1[i] * nv;
        float h0 = fmaxf(fmaf(s, w10, b10), 0.0f);
        float h1 = fmaxf(fmaf(s, w11, b11), 0.0f);
        float h2 = fmaxf(fmaf(s, w12, b12), 0.0f);
        t[i] = nv * (h0 * w20 + h1 * w21 + h2 * w22);
    }
}

__global__ void k5_out(const float* __restrict__ agg2, const float* __restrict__ norm,
                       const float* __restrict__ b2, float* __restrict__ out, int n) {
    float b = b2[0];
    int stride = gridDim.x * blockDim.x;
    for (int i = blockIdx.x * blockDim.x + threadIdx.x; i < n; i += stride) {
        out[i] = fmaxf(agg2[i] * norm[i] + b, 0.0f);
    }
}

// ---------------- binning pipeline ----------------

// H: per-chunk LDS histogram -> counts[b * nblk + chunk]  (transposed layout)
__global__ void k_hist(const int* __restrict__ dst, int nE, int NB, int chunk,
                       int* __restrict__ counts) {
    extern __shared__ int lhist[];
    for (int b = threadIdx.x; b < NB; b += blockDim.x) lhist[b] = 0;
    __syncthreads();
    int lo = blockIdx.x * chunk;
    int hi = min(lo + chunk, nE);
    for (int i = lo + (int)threadIdx.x; i < hi; i += blockDim.x)
        atomicAdd(&lhist[dst[i] >> BSHIFT], 1);
    __syncthreads();
    for (int b = threadIdx.x; b < NB; b += blockDim.x)
        counts[(size_t)b * NBIN_BLOCKS + blockIdx.x] = lhist[b];
}

// S1: one block per bucket — exclusive scan of its 1024 chunk counts (coalesced),
//     emit per-chunk prefixes and the bucket total. 256 threads x 4 elems.
__global__ void k_bucketscan(const int* __restrict__ counts,
                             int* __restrict__ chunkpre, int* __restrict__ tot) {
    __shared__ int ssum[256];
    int b = blockIdx.x;
    int t = threadIdx.x;
    const int4* in4 = (const int4*)(counts + (size_t)b * NBIN_BLOCKS);
    int4 v = in4[t];
    int mysum = v.x + v.y + v.z + v.w;
    ssum[t] = mysum;
    __syncthreads();
    // Hillis-Steele inclusive scan over 256 thread sums
    for (int ofs = 1; ofs < 256; ofs <<= 1) {
        int add = (t >= ofs) ? ssum[t - ofs] : 0;
        __syncthreads();
        ssum[t] += add;
        __syncthreads();
    }
    int excl = ssum[t] - mysum;
    int4 o;
    o.x = excl;
    o.y = excl + v.x;
    o.z = o.y + v.y;
    o.w = o.z + v.z;
    ((int4*)(chunkpre + (size_t)b * NBIN_BLOCKS))[t] = o;
    if (t == 255) tot[b] = ssum[255];
}

// S2: single small block — exclusive scan over NB bucket totals -> base[0..NB]
__global__ void k_exscan(const int* __restrict__ tot, int NB, int* __restrict__ base) {
    __shared__ int s[1024];
    int t = threadIdx.x;
    if (NB < 1024) {
        int v = (t < NB) ? tot[t] : 0;
        s[t] = v;
        __syncthreads();
        for (int ofs = 1; ofs < 1024; ofs <<= 1) {
            int add = (t >= ofs) ? s[t - ofs] : 0;
            __syncthreads();
            s[t] += add;
            __syncthreads();
        }
        if (t < NB) base[t] = s[t] - v;
        if (t == NB) base[NB] = s[NB - 1];
    } else if (t == 0) {  // fallback, never hit at these sizes
        int run = 0;
        for (int b = 0; b < NB; ++b) { base[b] = run; run += tot[b]; }
        base[NB] = run;
    }
}

// P: place packed edges bucket-contiguously. pack = (src<<BSHIFT)|dst_low.
__global__ void k_place(const int* __restrict__ src, const int* __restrict__ dst,
                        int nE, int NB, int chunk,
                        const int* __restrict__ chunkpre, const int* __restrict__ base,
                        unsigned int* __restrict__ bpack) {
    extern __shared__ int lcur[];
    for (int b = threadIdx.x; b < NB; b += blockDim.x)
        lcur[b] = chunkpre[(size_t)b * NBIN_BLOCKS + blockIdx.x] + base[b];
    __syncthreads();
    int lo = blockIdx.x * chunk;
    int hi = min(lo + chunk, nE);
    for (int i = lo + (int)threadIdx.x; i < hi; i += blockDim.x) {
        int d = dst[i];
        int b = d >> BSHIFT;
        int idx = atomicAdd(&lcur[b], 1);
        bpack[idx] = ((unsigned int)src[i] << BSHIFT) | (unsigned int)(d & (BSZ - 1));
    }
}

// B: one block per bucket — LDS accumulate, plain-store flush. No global atomics.
__global__ void k_bucket_acc(const unsigned int* __restrict__ bpack,
                             const int* __restrict__ base,
                             const float* __restrict__ val,
                             float* __restrict__ agg, int nN) {
    __shared__ float acc[BSZ];
    for (int j = threadIdx.x; j < BSZ; j += blockDim.x) acc[j] = 0.0f;
    __syncthreads();
    int b = blockIdx.x;
    int lo = base[b], hi = base[b + 1];
    for (int i = lo + (int)threadIdx.x; i < hi; i += blockDim.x) {
        unsigned int w = bpack[i];
        float v = val[w >> BSHIFT];
        atomicAdd(&acc[w & (BSZ - 1)], v);
    }
    __syncthreads();
    int node0 = b << BSHIFT;
    for (int j = threadIdx.x; j < BSZ && node0 + j < nN; j += blockDim.x)
        agg[node0 + j] = acc[j];
}

// ---------------- fallback: direct device-scope atomic scatter ----------------
__global__ void k_edge_scatter(const int* __restrict__ src, const int* __restrict__ dst,
                               const float* __restrict__ val, float* __restrict__ agg,
                               int nE) {
    int stride = gridDim.x * blockDim.x;
    for (int e = blockIdx.x * blockDim.x + threadIdx.x; e < nE; e += stride)
        atomicAdd(&agg[dst[e]], val[src[e]]);
}

static inline size_t align256(size_t x) { return (x + 255) & ~(size_t)255; }

extern "C" void kernel_launch(void* const* d_in, const int* in_sizes, int n_in,
                              void* d_out, int out_size, void* d_ws, size_t ws_size,
                              hipStream_t stream) {
    const float* feat = (const float*)d_in[0];
    const float* norm = (const float*)d_in[1];
    const int*   src  = (const int*)d_in[2];
    const int*   dst  = (const int*)d_in[3];
    const float* W1   = (const float*)d_in[4];
    const float* b1   = (const float*)d_in[5];
    const float* W2   = (const float*)d_in[6];
    const float* b2   = (const float*)d_in[7];
    float* out = (float*)d_out;

    int nN = in_sizes[0];
    int nE = in_sizes[2];
    int NB = (nN + BSZ - 1) >> BSHIFT;

    // workspace layout
    char* p = (char*)d_ws;
    size_t off = 0;
    float* g1   = (float*)(p + off); off = align256(off + (size_t)nN * 4);
    float* agg1 = (float*)(p + off); off = align256(off + (size_t)nN * 4);
    float* agg2 = (float*)(p + off); off = align256(off + (size_t)nN * 4);
    int* base     = (int*)(p + off); off = align256(off + (size_t)(NB + 1) * 4);
    int* tot      = (int*)(p + off); off = align256(off + (size_t)NB * 4);
    int* counts   = (int*)(p + off); off = align256(off + (size_t)NB * NBIN_BLOCKS * 4);
    int* chunkpre = (int*)(p + off); off = align256(off + (size_t)NB * NBIN_BLOCKS * 4);
    unsigned int* bpack = (unsigned int*)(p + off); off = align256(off + (size_t)nE * 4);
    size_t need = off;

    const int BLK = 256;
    int nodeBlocks = (nN + BLK - 1) / BLK;
    if (nodeBlocks > 2048) nodeBlocks = 2048;

    bool packed_ok = ((size_t)nN <= ((size_t)1 << (32 - BSHIFT)));
    if (ws_size >= need && packed_ok) {
        int chunk = (nE + NBIN_BLOCKS - 1) / NBIN_BLOCKS;
        size_t ldsNB = (size_t)NB * 4;

        k1_prep<<<nodeBlocks, BLK, 0, stream>>>(feat, norm, g1, agg1, agg2, nN);
        k_hist<<<NBIN_BLOCKS, 256, ldsNB, stream>>>(dst, nE, NB, chunk, counts);
        k_bucketscan<<<NB, 256, 0, stream>>>(counts, chunkpre, tot);
        k_exscan<<<1, 1024, 0, stream>>>(tot, NB, base);
        k_place<<<NBIN_BLOCKS, 256, ldsNB, stream>>>(src, dst, nE, NB, chunk,
                                                     chunkpre, base, bpack);
        k_bucket_acc<<<NB, 512, 0, stream>>>(bpack, base, g1, agg1, nN);
        k3_mid<<<nodeBlocks, BLK, 0, stream>>>(agg1, norm, W1, b1, W2, g1, nN);
        k_bucket_acc<<<NB, 512, 0, stream>>>(bpack, base, g1, agg2, nN);
        k5_out<<<nodeBlocks, BLK, 0, stream>>>(agg2, norm, b2, out, nN);
    } else {
        // fallback: direct atomic scatter (round-1 path)
        int edgeBlocks = 2048;
        k1_prep<<<nodeBlocks, BLK, 0, stream>>>(feat, norm, g1, agg1, agg2, nN);
        k_edge_scatter<<<edgeBlocks, BLK, 0, stream>>>(src, dst, g1, agg1, nE);
        k3_mid<<<nodeBlocks, BLK, 0, stream>>>(agg1, norm, W1, b1, W2, g1, nN);
        k_edge_scatter<<<edgeBlocks, BLK, 0, stream>>>(src, dst, g1, agg2, nE);
        k5_out<<<nodeBlocks, BLK, 0, stream>>>(agg2, norm, b2, out, nN);
    }
}

// Round 4
// 356.214 us; speedup vs baseline: 4.4037x; 1.1778x over previous
//
#include <hip/hip_runtime.h>

#define BSHIFT 11
#define BSZ (1 << BSHIFT)          // 2048 nodes per bucket
#define NBIN_BLOCKS 1024           // histogram/placement chunks
#define PB 512                     // k_place2 threads
#define BATCH 8192                 // edges sorted per LDS batch

// ---------------- node-map kernels ----------------

__global__ void k1_prep(const float* __restrict__ feat, const float* __restrict__ norm,
                        float* __restrict__ g1, float* __restrict__ agg1,
                        float* __restrict__ agg2, int n) {
    int stride = gridDim.x * blockDim.x;
    for (int i = blockIdx.x * blockDim.x + threadIdx.x; i < n; i += stride) {
        g1[i] = feat[i] * norm[i];
        agg1[i] = 0.0f;
        agg2[i] = 0.0f;
    }
}

__global__ void k3_mid(const float* __restrict__ agg1, const float* __restrict__ norm,
                       const float* __restrict__ W1, const float* __restrict__ b1,
                       const float* __restrict__ W2, float* __restrict__ t, int n) {
    float w10 = W1[0], w11 = W1[1], w12 = W1[2];
    float b10 = b1[0], b11 = b1[1], b12 = b1[2];
    float w20 = W2[0], w21 = W2[1], w22 = W2[2];
    int stride = gridDim.x * blockDim.x;
    for (int i = blockIdx.x * blockDim.x + threadIdx.x; i < n; i += stride) {
        float nv = norm[i];
        float s = agg1[i] * nv;
        float h0 = fmaxf(fmaf(s, w10, b10), 0.0f);
        float h1 = fmaxf(fmaf(s, w11, b11), 0.0f);
        float h2 = fmaxf(fmaf(s, w12, b12), 0.0f);
        t[i] = nv * (h0 * w20 + h1 * w21 + h2 * w22);
    }
}

__global__ void k5_out(const float* __restrict__ agg2, const float* __restrict__ norm,
                       const float* __restrict__ b2, float* __restrict__ out, int n) {
    float b = b2[0];
    int stride = gridDim.x * blockDim.x;
    for (int i = blockIdx.x * blockDim.x + threadIdx.x; i < n; i += stride) {
        out[i] = fmaxf(agg2[i] * norm[i] + b, 0.0f);
    }
}

// ---------------- binning pipeline ----------------

// H: per-chunk LDS histogram -> counts[b * NBIN_BLOCKS + chunk]  (transposed)
__global__ void k_hist(const int* __restrict__ dst, int nE, int NB, int chunk,
                       int* __restrict__ counts) {
    extern __shared__ int lhist[];
    for (int b = threadIdx.x; b < NB; b += blockDim.x) lhist[b] = 0;
    __syncthreads();
    int lo = blockIdx.x * chunk;
    int hi = min(lo + chunk, nE);
    for (int i = lo + (int)threadIdx.x; i < hi; i += blockDim.x)
        atomicAdd(&lhist[dst[i] >> BSHIFT], 1);
    __syncthreads();
    for (int b = threadIdx.x; b < NB; b += blockDim.x)
        counts[(size_t)b * NBIN_BLOCKS + blockIdx.x] = lhist[b];
}

// S1: one block per bucket — exclusive scan of its 1024 chunk counts.
__global__ void k_bucketscan(const int* __restrict__ counts,
                             int* __restrict__ chunkpre, int* __restrict__ tot) {
    __shared__ int ssum[256];
    int b = blockIdx.x;
    int t = threadIdx.x;
    const int4* in4 = (const int4*)(counts + (size_t)b * NBIN_BLOCKS);
    int4 v = in4[t];
    int mysum = v.x + v.y + v.z + v.w;
    ssum[t] = mysum;
    __syncthreads();
    for (int ofs = 1; ofs < 256; ofs <<= 1) {
        int add = (t >= ofs) ? ssum[t - ofs] : 0;
        __syncthreads();
        ssum[t] += add;
        __syncthreads();
    }
    int excl = ssum[t] - mysum;
    int4 o;
    o.x = excl;
    o.y = excl + v.x;
    o.z = o.y + v.y;
    o.w = o.z + v.z;
    ((int4*)(chunkpre + (size_t)b * NBIN_BLOCKS))[t] = o;
    if (t == 255) tot[b] = ssum[255];
}

// S2: exclusive scan over NB bucket totals -> base[0..NB]
__global__ void k_exscan(const int* __restrict__ tot, int NB, int* __restrict__ base) {
    __shared__ int s[1024];
    int t = threadIdx.x;
    if (NB < 1024) {
        int v = (t < NB) ? tot[t] : 0;
        s[t] = v;
        __syncthreads();
        for (int ofs = 1; ofs < 1024; ofs <<= 1) {
            int add = (t >= ofs) ? s[t - ofs] : 0;
            __syncthreads();
            s[t] += add;
            __syncthreads();
        }
        if (t < NB) base[t] = s[t] - v;
        if (t == NB) base[NB] = s[NB - 1];
    } else if (t == 0) {
        int run = 0;
        for (int b = 0; b < NB; ++b) { base[b] = run; run += tot[b]; }
        base[NB] = run;
    }
}

// P2: LDS-sorted placement. Per 8192-edge batch: histogram -> scan -> sorted
// pack into LDS -> linear flush (coalesced per-bucket segments).
__global__ void __launch_bounds__(PB)
k_place2(const int* __restrict__ src, const int* __restrict__ dst,
         int nE, int NB, int chunk,
         const int* __restrict__ chunkpre, const int* __restrict__ base,
         unsigned int* __restrict__ bpack) {
    __shared__ unsigned int spack[BATCH];  // 32 KB sorted packed edges
    __shared__ int lcur[512];              // histogram, then local cursor
    __shared__ int loff[513];              // exclusive offsets (binary search)
    __shared__ int gcur[512];              // global cursor per bucket
    __shared__ int ssc[512];               // scan buffer
    int t = threadIdx.x;
    int blk = blockIdx.x;

    for (int b = t; b < NB; b += PB)
        gcur[b] = base[b] + chunkpre[(size_t)b * NBIN_BLOCKS + blk];

    int lo = blk * chunk;
    int hi = min(lo + chunk, nE);
    for (int bs = lo; bs < hi; bs += BATCH) {
        int be = min(bs + BATCH, hi);
        int cnt = be - bs;
        lcur[t] = 0;                       // PB==512 covers all 512 entries
        __syncthreads();
        // phase A: batch histogram
        for (int i = bs + t; i < be; i += PB)
            atomicAdd(&lcur[dst[i] >> BSHIFT], 1);
        __syncthreads();
        // scan 512 entries (Hillis-Steele inclusive), derive exclusive
        int v = lcur[t];
        ssc[t] = v;
        __syncthreads();
        for (int ofs = 1; ofs < 512; ofs <<= 1) {
            int add = (t >= ofs) ? ssc[t - ofs] : 0;
            __syncthreads();
            ssc[t] += add;
            __syncthreads();
        }
        int excl = ssc[t] - v;
        loff[t] = excl;
        lcur[t] = excl;                    // cursor starts at bucket offset
        if (t == 511) loff[512] = ssc[511];
        __syncthreads();
        // phase B: sorted scatter into LDS
        for (int i = bs + t; i < be; i += PB) {
            int d = dst[i];
            int b = d >> BSHIFT;
            int pos = atomicAdd(&lcur[b], 1);
            spack[pos] = ((unsigned int)src[i] << BSHIFT) | (unsigned int)(d & (BSZ - 1));
        }
        __syncthreads();
        // flush: linear LDS -> per-bucket contiguous global segments
        for (int j = t; j < cnt; j += PB) {
            int blo = 0, bhi = NB;         // invariant: loff[blo] <= j < loff[bhi]
            while (bhi - blo > 1) {
                int mid = (blo + bhi) >> 1;
                if (loff[mid] <= j) blo = mid; else bhi = mid;
            }
            bpack[gcur[blo] + (j - loff[blo])] = spack[j];
        }
        __syncthreads();
        // advance global cursors
        for (int b = t; b < NB; b += PB)
            gcur[b] += loff[b + 1] - loff[b];
        __syncthreads();
    }
}

// B: one block per bucket — LDS accumulate, plain-store flush.
__global__ void k_bucket_acc(const unsigned int* __restrict__ bpack,
                             const int* __restrict__ base,
                             const float* __restrict__ val,
                             float* __restrict__ agg, int nN) {
    __shared__ float acc[BSZ];
    for (int j = threadIdx.x; j < BSZ; j += blockDim.x) acc[j] = 0.0f;
    __syncthreads();
    int b = blockIdx.x;
    int lo = base[b], hi = base[b + 1];
    for (int i = lo + (int)threadIdx.x; i < hi; i += blockDim.x) {
        unsigned int w = bpack[i];
        float v = val[w >> BSHIFT];
        atomicAdd(&acc[w & (BSZ - 1)], v);
    }
    __syncthreads();
    int node0 = b << BSHIFT;
    for (int j = threadIdx.x; j < BSZ && node0 + j < nN; j += blockDim.x)
        agg[node0 + j] = acc[j];
}

// ---------------- fallback: direct device-scope atomic scatter ----------------
__global__ void k_edge_scatter(const int* __restrict__ src, const int* __restrict__ dst,
                               const float* __restrict__ val, float* __restrict__ agg,
                               int nE) {
    int stride = gridDim.x * blockDim.x;
    for (int e = blockIdx.x * blockDim.x + threadIdx.x; e < nE; e += stride)
        atomicAdd(&agg[dst[e]], val[src[e]]);
}

static inline size_t align256(size_t x) { return (x + 255) & ~(size_t)255; }

extern "C" void kernel_launch(void* const* d_in, const int* in_sizes, int n_in,
                              void* d_out, int out_size, void* d_ws, size_t ws_size,
                              hipStream_t stream) {
    const float* feat = (const float*)d_in[0];
    const float* norm = (const float*)d_in[1];
    const int*   src  = (const int*)d_in[2];
    const int*   dst  = (const int*)d_in[3];
    const float* W1   = (const float*)d_in[4];
    const float* b1   = (const float*)d_in[5];
    const float* W2   = (const float*)d_in[6];
    const float* b2   = (const float*)d_in[7];
    float* out = (float*)d_out;

    int nN = in_sizes[0];
    int nE = in_sizes[2];
    int NB = (nN + BSZ - 1) >> BSHIFT;

    // workspace layout
    char* p = (char*)d_ws;
    size_t off = 0;
    float* g1   = (float*)(p + off); off = align256(off + (size_t)nN * 4);
    float* agg1 = (float*)(p + off); off = align256(off + (size_t)nN * 4);
    float* agg2 = (float*)(p + off); off = align256(off + (size_t)nN * 4);
    int* base     = (int*)(p + off); off = align256(off + (size_t)(NB + 1) * 4);
    int* tot      = (int*)(p + off); off = align256(off + (size_t)NB * 4);
    int* counts   = (int*)(p + off); off = align256(off + (size_t)NB * NBIN_BLOCKS * 4);
    int* chunkpre = (int*)(p + off); off = align256(off + (size_t)NB * NBIN_BLOCKS * 4);
    unsigned int* bpack = (unsigned int*)(p + off); off = align256(off + (size_t)nE * 4);
    size_t need = off;

    const int BLK = 256;
    int nodeBlocks = (nN + BLK - 1) / BLK;
    if (nodeBlocks > 2048) nodeBlocks = 2048;

    bool packed_ok = ((size_t)nN <= ((size_t)1 << (32 - BSHIFT))) && (NB <= 512);
    if (ws_size >= need && packed_ok) {
        int chunk = (nE + NBIN_BLOCKS - 1) / NBIN_BLOCKS;
        size_t ldsNB = (size_t)NB * 4;

        k1_prep<<<nodeBlocks, BLK, 0, stream>>>(feat, norm, g1, agg1, agg2, nN);
        k_hist<<<NBIN_BLOCKS, 256, ldsNB, stream>>>(dst, nE, NB, chunk, counts);
        k_bucketscan<<<NB, 256, 0, stream>>>(counts, chunkpre, tot);
        k_exscan<<<1, 1024, 0, stream>>>(tot, NB, base);
        k_place2<<<NBIN_BLOCKS, PB, 0, stream>>>(src, dst, nE, NB, chunk,
                                                 chunkpre, base, bpack);
        k_bucket_acc<<<NB, 512, 0, stream>>>(bpack, base, g1, agg1, nN);
        k3_mid<<<nodeBlocks, BLK, 0, stream>>>(agg1, norm, W1, b1, W2, g1, nN);
        k_bucket_acc<<<NB, 512, 0, stream>>>(bpack, base, g1, agg2, nN);
        k5_out<<<nodeBlocks, BLK, 0, stream>>>(agg2, norm, b2, out, nN);
    } else {
        // fallback: direct atomic scatter (round-1 path)
        int edgeBlocks = 2048;
        k1_prep<<<nodeBlocks, BLK, 0, stream>>>(feat, norm, g1, agg1, agg2, nN);
        k_edge_scatter<<<edgeBlocks, BLK, 0, stream>>>(src, dst, g1, agg1, nE);
        k3_mid<<<nodeBlocks, BLK, 0, stream>>>(agg1, norm, W1, b1, W2, g1, nN);
        k_edge_scatter<<<edgeBlocks, BLK, 0, stream>>>(src, dst, g1, agg2, nE);
        k5_out<<<nodeBlocks, BLK, 0, stream>>>(agg2, norm, b2, out, nN);
    }
}

// Round 5
// 264.645 us; speedup vs baseline: 5.9274x; 1.3460x over previous
//
#include <hip/hip_runtime.h>

#define BSHIFT 11
#define BSZ (1 << BSHIFT)          // 2048 nodes per bucket
#define NBIN_BLOCKS 1024           // histogram/placement chunks
#define PB 512                     // k_place2 threads
#define BATCH 8192                 // edges sorted per LDS batch

// ---------------- node-map kernels ----------------

// binned path: only g1 = feat*norm (no zeroing needed — acc kernels overwrite)
__global__ void k1b(const float* __restrict__ feat, const float* __restrict__ norm,
                    float* __restrict__ g1, int n) {
    int stride = gridDim.x * blockDim.x;
    for (int i = blockIdx.x * blockDim.x + threadIdx.x; i < n; i += stride)
        g1[i] = feat[i] * norm[i];
}

// fallback path helpers
__global__ void k1_prep(const float* __restrict__ feat, const float* __restrict__ norm,
                        float* __restrict__ g1, float* __restrict__ agg1,
                        float* __restrict__ agg2, int n) {
    int stride = gridDim.x * blockDim.x;
    for (int i = blockIdx.x * blockDim.x + threadIdx.x; i < n; i += stride) {
        g1[i] = feat[i] * norm[i];
        agg1[i] = 0.0f;
        agg2[i] = 0.0f;
    }
}

__global__ void k3_mid(const float* __restrict__ agg1, const float* __restrict__ norm,
                       const float* __restrict__ W1, const float* __restrict__ b1,
                       const float* __restrict__ W2, float* __restrict__ t, int n) {
    float w10 = W1[0], w11 = W1[1], w12 = W1[2];
    float b10 = b1[0], b11 = b1[1], b12 = b1[2];
    float w20 = W2[0], w21 = W2[1], w22 = W2[2];
    int stride = gridDim.x * blockDim.x;
    for (int i = blockIdx.x * blockDim.x + threadIdx.x; i < n; i += stride) {
        float nv = norm[i];
        float s = agg1[i] * nv;
        float h0 = fmaxf(fmaf(s, w10, b10), 0.0f);
        float h1 = fmaxf(fmaf(s, w11, b11), 0.0f);
        float h2 = fmaxf(fmaf(s, w12, b12), 0.0f);
        t[i] = nv * (h0 * w20 + h1 * w21 + h2 * w22);
    }
}

__global__ void k5_out(const float* __restrict__ agg2, const float* __restrict__ norm,
                       const float* __restrict__ b2, float* __restrict__ out, int n) {
    float b = b2[0];
    int stride = gridDim.x * blockDim.x;
    for (int i = blockIdx.x * blockDim.x + threadIdx.x; i < n; i += stride)
        out[i] = fmaxf(agg2[i] * norm[i] + b, 0.0f);
}

// ---------------- binning pipeline ----------------

// H: per-chunk LDS histogram -> counts[b * NBIN_BLOCKS + chunk]  (transposed)
__global__ void k_hist(const int* __restrict__ dst, int nE, int NB, int chunk,
                       int* __restrict__ counts) {
    extern __shared__ int lhist[];
    int t = threadIdx.x;
    for (int b = t; b < NB; b += blockDim.x) lhist[b] = 0;
    __syncthreads();
    int lo = blockIdx.x * chunk;
    int hi = min(lo + chunk, nE);
    int n4 = (hi - lo) >> 2;                       // lo % 4 == 0 (chunk % 4 == 0)
    const int4* d4 = (const int4*)(dst + lo);
    for (int i = t; i < n4; i += blockDim.x) {
        int4 v = d4[i];
        atomicAdd(&lhist[v.x >> BSHIFT], 1);
        atomicAdd(&lhist[v.y >> BSHIFT], 1);
        atomicAdd(&lhist[v.z >> BSHIFT], 1);
        atomicAdd(&lhist[v.w >> BSHIFT], 1);
    }
    for (int i = lo + (n4 << 2) + t; i < hi; i += blockDim.x)
        atomicAdd(&lhist[dst[i] >> BSHIFT], 1);
    __syncthreads();
    for (int b = t; b < NB; b += blockDim.x)
        counts[(size_t)b * NBIN_BLOCKS + blockIdx.x] = lhist[b];
}

// S1: one block per bucket — exclusive scan of its 1024 chunk counts.
__global__ void k_bucketscan(const int* __restrict__ counts,
                             int* __restrict__ chunkpre, int* __restrict__ tot) {
    __shared__ int ssum[256];
    int b = blockIdx.x;
    int t = threadIdx.x;
    const int4* in4 = (const int4*)(counts + (size_t)b * NBIN_BLOCKS);
    int4 v = in4[t];
    int mysum = v.x + v.y + v.z + v.w;
    ssum[t] = mysum;
    __syncthreads();
    for (int ofs = 1; ofs < 256; ofs <<= 1) {
        int add = (t >= ofs) ? ssum[t - ofs] : 0;
        __syncthreads();
        ssum[t] += add;
        __syncthreads();
    }
    int excl = ssum[t] - mysum;
    int4 o;
    o.x = excl;
    o.y = excl + v.x;
    o.z = o.y + v.y;
    o.w = o.z + v.z;
    ((int4*)(chunkpre + (size_t)b * NBIN_BLOCKS))[t] = o;
    if (t == 255) tot[b] = ssum[255];
}

// S2: exclusive scan over NB bucket totals -> base[0..NB]
__global__ void k_exscan(const int* __restrict__ tot, int NB, int* __restrict__ base) {
    __shared__ int s[1024];
    int t = threadIdx.x;
    if (NB < 1024) {
        int v = (t < NB) ? tot[t] : 0;
        s[t] = v;
        __syncthreads();
        for (int ofs = 1; ofs < 1024; ofs <<= 1) {
            int add = (t >= ofs) ? s[t - ofs] : 0;
            __syncthreads();
            s[t] += add;
            __syncthreads();
        }
        if (t < NB) base[t] = s[t] - v;
        if (t == NB) base[NB] = s[NB - 1];
    } else if (t == 0) {
        int run = 0;
        for (int b = 0; b < NB; ++b) { base[b] = run; run += tot[b]; }
        base[NB] = run;
    }
}

// P2: LDS-sorted placement; bucket id recorded per slot (no binary search).
__global__ void __launch_bounds__(PB)
k_place2(const int* __restrict__ src, const int* __restrict__ dst,
         int nE, int NB, int chunk,
         const int* __restrict__ chunkpre, const int* __restrict__ base,
         unsigned int* __restrict__ bpack) {
    __shared__ unsigned int spack[BATCH];      // 32 KB sorted packed edges
    __shared__ unsigned short sbkt[BATCH];     // 16 KB bucket id per slot
    __shared__ int lcur[512];
    __shared__ int loff[513];
    __shared__ int gcur[512];
    __shared__ int ssc[512];
    int t = threadIdx.x;
    int blk = blockIdx.x;

    for (int b = t; b < NB; b += PB)
        gcur[b] = base[b] + chunkpre[(size_t)b * NBIN_BLOCKS + blk];

    int lo = blk * chunk;
    int hi = min(lo + chunk, nE);
    for (int bs = lo; bs < hi; bs += BATCH) {
        int be = min(bs + BATCH, hi);
        int cnt = be - bs;
        lcur[t] = 0;
        __syncthreads();
        // phase A: batch histogram (int4 loads; bs % 4 == 0)
        int n4 = cnt >> 2;
        const int4* d4 = (const int4*)(dst + bs);
        for (int i = t; i < n4; i += PB) {
            int4 v = d4[i];
            atomicAdd(&lcur[v.x >> BSHIFT], 1);
            atomicAdd(&lcur[v.y >> BSHIFT], 1);
            atomicAdd(&lcur[v.z >> BSHIFT], 1);
            atomicAdd(&lcur[v.w >> BSHIFT], 1);
        }
        for (int i = bs + (n4 << 2) + t; i < be; i += PB)
            atomicAdd(&lcur[dst[i] >> BSHIFT], 1);
        __syncthreads();
        // scan 512 (Hillis-Steele inclusive) -> exclusive offsets
        int v = lcur[t];
        ssc[t] = v;
        __syncthreads();
        for (int ofs = 1; ofs < 512; ofs <<= 1) {
            int add = (t >= ofs) ? ssc[t - ofs] : 0;
            __syncthreads();
            ssc[t] += add;
            __syncthreads();
        }
        int excl = ssc[t] - v;
        loff[t] = excl;
        lcur[t] = excl;
        if (t == 511) loff[512] = ssc[511];
        __syncthreads();
        // phase B: sorted scatter into LDS (int4 loads of src+dst)
        const int4* s4 = (const int4*)(src + bs);
        for (int i = t; i < n4; i += PB) {
            int4 dv = d4[i];
            int4 sv = s4[i];
            int b0 = dv.x >> BSHIFT, p0 = atomicAdd(&lcur[b0], 1);
            spack[p0] = ((unsigned int)sv.x << BSHIFT) | (unsigned int)(dv.x & (BSZ - 1));
            sbkt[p0] = (unsigned short)b0;
            int b1 = dv.y >> BSHIFT, p1 = atomicAdd(&lcur[b1], 1);
            spack[p1] = ((unsigned int)sv.y << BSHIFT) | (unsigned int)(dv.y & (BSZ - 1));
            sbkt[p1] = (unsigned short)b1;
            int b2 = dv.z >> BSHIFT, p2 = atomicAdd(&lcur[b2], 1);
            spack[p2] = ((unsigned int)sv.z << BSHIFT) | (unsigned int)(dv.z & (BSZ - 1));
            sbkt[p2] = (unsigned short)b2;
            int b3 = dv.w >> BSHIFT, p3 = atomicAdd(&lcur[b3], 1);
            spack[p3] = ((unsigned int)sv.w << BSHIFT) | (unsigned int)(dv.w & (BSZ - 1));
            sbkt[p3] = (unsigned short)b3;
        }
        for (int i = bs + (n4 << 2) + t; i < be; i += PB) {
            int d = dst[i];
            int b = d >> BSHIFT;
            int pos = atomicAdd(&lcur[b], 1);
            spack[pos] = ((unsigned int)src[i] << BSHIFT) | (unsigned int)(d & (BSZ - 1));
            sbkt[pos] = (unsigned short)b;
        }
        __syncthreads();
        // flush: direct bucket lookup, per-bucket contiguous global segments
        for (int j = t; j < cnt; j += PB) {
            int b = sbkt[j];
            bpack[gcur[b] + (j - loff[b])] = spack[j];
        }
        __syncthreads();
        for (int b = t; b < NB; b += PB)
            gcur[b] += loff[b + 1] - loff[b];
        __syncthreads();
    }
}

// A1: bucket accumulate of g1 + fused layer-1 MLP -> t[node]
__global__ void k_acc1(const unsigned int* __restrict__ bpack,
                       const int* __restrict__ base,
                       const float* __restrict__ val, const float* __restrict__ norm,
                       const float* __restrict__ W1, const float* __restrict__ b1,
                       const float* __restrict__ W2,
                       float* __restrict__ t, int nN) {
    __shared__ float acc[BSZ];
    for (int j = threadIdx.x; j < BSZ; j += blockDim.x) acc[j] = 0.0f;
    __syncthreads();
    int b = blockIdx.x;
    int lo = base[b], hi = base[b + 1];
    // head to 4-alignment
    int head = min((4 - (lo & 3)) & 3, hi - lo);
    for (int i = lo + (int)threadIdx.x; i < lo + head; i += blockDim.x) {
        unsigned int w = bpack[i];
        atomicAdd(&acc[w & (BSZ - 1)], val[w >> BSHIFT]);
    }
    int lo4 = lo + head;
    int n4 = (hi - lo4) >> 2;
    const uint4* p4 = (const uint4*)(bpack + lo4);
    for (int i = threadIdx.x; i < n4; i += blockDim.x) {
        uint4 w = p4[i];
        atomicAdd(&acc[w.x & (BSZ - 1)], val[w.x >> BSHIFT]);
        atomicAdd(&acc[w.y & (BSZ - 1)], val[w.y >> BSHIFT]);
        atomicAdd(&acc[w.z & (BSZ - 1)], val[w.z >> BSHIFT]);
        atomicAdd(&acc[w.w & (BSZ - 1)], val[w.w >> BSHIFT]);
    }
    for (int i = lo4 + (n4 << 2) + (int)threadIdx.x; i < hi; i += blockDim.x) {
        unsigned int w = bpack[i];
        atomicAdd(&acc[w & (BSZ - 1)], val[w >> BSHIFT]);
    }
    __syncthreads();
    float w10 = W1[0], w11 = W1[1], w12 = W1[2];
    float b10 = b1[0], b11 = b1[1], b12 = b1[2];
    float w20 = W2[0], w21 = W2[1], w22 = W2[2];
    int node0 = b << BSHIFT;
    for (int j = threadIdx.x; j < BSZ && node0 + j < nN; j += blockDim.x) {
        float nv = norm[node0 + j];
        float s = acc[j] * nv;
        float h0 = fmaxf(fmaf(s, w10, b10), 0.0f);
        float h1 = fmaxf(fmaf(s, w11, b11), 0.0f);
        float h2 = fmaxf(fmaf(s, w12, b12), 0.0f);
        t[node0 + j] = nv * (h0 * w20 + h1 * w21 + h2 * w22);
    }
}

// A2: bucket accumulate of t + fused output relu -> out[node]
__global__ void k_acc2(const unsigned int* __restrict__ bpack,
                       const int* __restrict__ base,
                       const float* __restrict__ val, const float* __restrict__ norm,
                       const float* __restrict__ b2,
                       float* __restrict__ out, int nN) {
    __shared__ float acc[BSZ];
    for (int j = threadIdx.x; j < BSZ; j += blockDim.x) acc[j] = 0.0f;
    __syncthreads();
    int b = blockIdx.x;
    int lo = base[b], hi = base[b + 1];
    int head = min((4 - (lo & 3)) & 3, hi - lo);
    for (int i = lo + (int)threadIdx.x; i < lo + head; i += blockDim.x) {
        unsigned int w = bpack[i];
        atomicAdd(&acc[w & (BSZ - 1)], val[w >> BSHIFT]);
    }
    int lo4 = lo + head;
    int n4 = (hi - lo4) >> 2;
    const uint4* p4 = (const uint4*)(bpack + lo4);
    for (int i = threadIdx.x; i < n4; i += blockDim.x) {
        uint4 w = p4[i];
        atomicAdd(&acc[w.x & (BSZ - 1)], val[w.x >> BSHIFT]);
        atomicAdd(&acc[w.y & (BSZ - 1)], val[w.y >> BSHIFT]);
        atomicAdd(&acc[w.z & (BSZ - 1)], val[w.z >> BSHIFT]);
        atomicAdd(&acc[w.w & (BSZ - 1)], val[w.w >> BSHIFT]);
    }
    for (int i = lo4 + (n4 << 2) + (int)threadIdx.x; i < hi; i += blockDim.x) {
        unsigned int w = bpack[i];
        atomicAdd(&acc[w & (BSZ - 1)], val[w >> BSHIFT]);
    }
    __syncthreads();
    float bb = b2[0];
    int node0 = b << BSHIFT;
    for (int j = threadIdx.x; j < BSZ && node0 + j < nN; j += blockDim.x)
        out[node0 + j] = fmaxf(acc[j] * norm[node0 + j] + bb, 0.0f);
}

// ---------------- fallback: direct device-scope atomic scatter ----------------
__global__ void k_edge_scatter(const int* __restrict__ src, const int* __restrict__ dst,
                               const float* __restrict__ val, float* __restrict__ agg,
                               int nE) {
    int stride = gridDim.x * blockDim.x;
    for (int e = blockIdx.x * blockDim.x + threadIdx.x; e < nE; e += stride)
        atomicAdd(&agg[dst[e]], val[src[e]]);
}

static inline size_t align256(size_t x) { return (x + 255) & ~(size_t)255; }

extern "C" void kernel_launch(void* const* d_in, const int* in_sizes, int n_in,
                              void* d_out, int out_size, void* d_ws, size_t ws_size,
                              hipStream_t stream) {
    const float* feat = (const float*)d_in[0];
    const float* norm = (const float*)d_in[1];
    const int*   src  = (const int*)d_in[2];
    const int*   dst  = (const int*)d_in[3];
    const float* W1   = (const float*)d_in[4];
    const float* b1   = (const float*)d_in[5];
    const float* W2   = (const float*)d_in[6];
    const float* b2   = (const float*)d_in[7];
    float* out = (float*)d_out;

    int nN = in_sizes[0];
    int nE = in_sizes[2];
    int NB = (nN + BSZ - 1) >> BSHIFT;

    // workspace layout
    char* p = (char*)d_ws;
    size_t off = 0;
    float* g1   = (float*)(p + off); off = align256(off + (size_t)nN * 4);
    float* agg1 = (float*)(p + off); off = align256(off + (size_t)nN * 4);
    float* agg2 = (float*)(p + off); off = align256(off + (size_t)nN * 4);
    int* base     = (int*)(p + off); off = align256(off + (size_t)(NB + 1) * 4);
    int* tot      = (int*)(p + off); off = align256(off + (size_t)NB * 4);
    int* counts   = (int*)(p + off); off = align256(off + (size_t)NB * NBIN_BLOCKS * 4);
    int* chunkpre = (int*)(p + off); off = align256(off + (size_t)NB * NBIN_BLOCKS * 4);
    unsigned int* bpack = (unsigned int*)(p + off); off = align256(off + (size_t)nE * 4);
    size_t need = off;

    const int BLK = 256;
    int nodeBlocks = (nN + BLK - 1) / BLK;
    if (nodeBlocks > 2048) nodeBlocks = 2048;

    bool packed_ok = ((size_t)nN <= ((size_t)1 << (32 - BSHIFT))) && (NB <= 512);
    if (ws_size >= need && packed_ok) {
        // chunk: multiple of 4 so int4 loads stay aligned
        int chunk = (nE + NBIN_BLOCKS - 1) / NBIN_BLOCKS;
        chunk = (chunk + 3) & ~3;
        size_t ldsNB = (size_t)NB * 4;

        k1b<<<nodeBlocks, BLK, 0, stream>>>(feat, norm, g1, nN);
        k_hist<<<NBIN_BLOCKS, 256, ldsNB, stream>>>(dst, nE, NB, chunk, counts);
        k_bucketscan<<<NB, 256, 0, stream>>>(counts, chunkpre, tot);
        k_exscan<<<1, 1024, 0, stream>>>(tot, NB, base);
        k_place2<<<NBIN_BLOCKS, PB, 0, stream>>>(src, dst, nE, NB, chunk,
                                                 chunkpre, base, bpack);
        k_acc1<<<NB, 512, 0, stream>>>(bpack, base, g1, norm, W1, b1, W2, agg1, nN);
        k_acc2<<<NB, 512, 0, stream>>>(bpack, base, agg1, norm, b2, out, nN);
    } else {
        // fallback: direct atomic scatter (round-1 path)
        int edgeBlocks = 2048;
        k1_prep<<<nodeBlocks, BLK, 0, stream>>>(feat, norm, g1, agg1, agg2, nN);
        k_edge_scatter<<<edgeBlocks, BLK, 0, stream>>>(src, dst, g1, agg1, nE);
        k3_mid<<<nodeBlocks, BLK, 0, stream>>>(agg1, norm, W1, b1, W2, g1, nN);
        k_edge_scatter<<<edgeBlocks, BLK, 0, stream>>>(src, dst, g1, agg2, nE);
        k5_out<<<nodeBlocks, BLK, 0, stream>>>(agg2, norm, b2, out, nN);
    }
}